// Round 2
// baseline (238.016 us; speedup 1.0000x reference)
//
#include <hip/hip_runtime.h>
#include <math.h>

#define AS1 __attribute__((address_space(1)))
#define AS3 __attribute__((address_space(3)))

typedef __attribute__((ext_vector_type(8))) short bf16x8;
typedef __attribute__((ext_vector_type(4))) float f32x4;

__device__ __forceinline__ unsigned short f2bf(float f) {
    union { float f; unsigned int i; } v; v.f = f;
    unsigned int r = v.i + 0x7FFFu + ((v.i >> 16) & 1u);  // RNE
    return (unsigned short)(r >> 16);
}

__device__ __forceinline__ void store_out(float* p, float v) { *p = v; }
__device__ __forceinline__ void store_out(unsigned short* p, float v) { *p = f2bf(v); }

// ---------------------------------------------------------------------------
// fp32 -> bf16 elementwise convert (n % 4 == 0)
// ---------------------------------------------------------------------------
__global__ void f32_to_bf16(const float* __restrict__ src,
                            unsigned short* __restrict__ dst, int n4)
{
    int i = blockIdx.x * blockDim.x + threadIdx.x;
    if (i < n4) {
        const float4 v = ((const float4*)src)[i];
        ushort4 o;
        o.x = f2bf(v.x); o.y = f2bf(v.y); o.z = f2bf(v.z); o.w = f2bf(v.w);
        ((ushort4*)dst)[i] = o;
    }
}

// ---------------------------------------------------------------------------
// GEMM: C[m][n] = sum_k A[m][k] * W[n][k] + bias[n]   (A: MxK, W: NxK, both
// row-major bf16, K contiguous). m97 structure: 128x128 tile, BK=32, 4 waves
// 2x2, global_load_lds width=16. Requires M%128==0, N%128==0, K%32==0.
// Bias fp32; output type templated (bf16 intermediate / fp32 final).
// ---------------------------------------------------------------------------
template <typename OutT>
__global__ __launch_bounds__(256, 2)
void gemm_bt_128(const unsigned short* __restrict__ A,
                 const unsigned short* __restrict__ W,
                 const float* __restrict__ bias,
                 OutT* __restrict__ Cmat,
                 int M, int N, int K)
{
    __shared__ __align__(16) unsigned short As[128 * 32];
    __shared__ __align__(16) unsigned short Bs[128 * 32];

    const int tid  = threadIdx.x;
    const int wave = tid >> 6;
    const int lane = tid & 63;
    const int quad = lane >> 4;
    const int l15  = lane & 15;
    const int wr   = wave >> 1;   // wave row 0..1 (64 rows each)
    const int wc   = wave & 1;    // wave col 0..1

    const int m0 = blockIdx.x * 128;
    const int n0 = blockIdx.y * 128;

    const int srow = wave * 32 + (lane >> 2);
    const int scol = (lane & 3) * 8;

    const unsigned short* Ag0 = A + (size_t)(m0 + srow) * K + scol;
    const unsigned short* Ag1 = A + (size_t)(m0 + srow + 16) * K + scol;
    const unsigned short* Wg0 = W + (size_t)(n0 + srow) * K + scol;
    const unsigned short* Wg1 = W + (size_t)(n0 + srow + 16) * K + scol;

    unsigned short* As0 = As + (wave * 2 + 0) * 512 + lane * 8;
    unsigned short* As1 = As + (wave * 2 + 1) * 512 + lane * 8;
    unsigned short* Bs0 = Bs + (wave * 2 + 0) * 512 + lane * 8;
    unsigned short* Bs1 = Bs + (wave * 2 + 1) * 512 + lane * 8;

    f32x4 acc[4][4];
#pragma unroll
    for (int i = 0; i < 4; ++i)
#pragma unroll
        for (int j = 0; j < 4; ++j) acc[i][j] = (f32x4){0.f, 0.f, 0.f, 0.f};

    for (int k0 = 0; k0 < K; k0 += 32) {
        __syncthreads();
        __builtin_amdgcn_global_load_lds((AS1 void*)(Ag0 + k0), (AS3 void*)As0, 16, 0, 0);
        __builtin_amdgcn_global_load_lds((AS1 void*)(Ag1 + k0), (AS3 void*)As1, 16, 0, 0);
        __builtin_amdgcn_global_load_lds((AS1 void*)(Wg0 + k0), (AS3 void*)Bs0, 16, 0, 0);
        __builtin_amdgcn_global_load_lds((AS1 void*)(Wg1 + k0), (AS3 void*)Bs1, 16, 0, 0);
        __syncthreads();

        bf16x8 af[4], bfr[4];
#pragma unroll
        for (int i = 0; i < 4; ++i)
            af[i] = *(const bf16x8*)(As + (wr * 64 + i * 16 + l15) * 32 + quad * 8);
#pragma unroll
        for (int j = 0; j < 4; ++j)
            bfr[j] = *(const bf16x8*)(Bs + (wc * 64 + j * 16 + l15) * 32 + quad * 8);
#pragma unroll
        for (int i = 0; i < 4; ++i)
#pragma unroll
            for (int j = 0; j < 4; ++j)
                acc[i][j] = __builtin_amdgcn_mfma_f32_16x16x32_bf16(af[i], bfr[j], acc[i][j], 0, 0, 0);
    }

    // epilogue: C/D layout col=lane&15, row=quad*4+r
#pragma unroll
    for (int i = 0; i < 4; ++i) {
        const int row = m0 + wr * 64 + i * 16 + quad * 4;
#pragma unroll
        for (int j = 0; j < 4; ++j) {
            const int col = n0 + wc * 64 + j * 16 + l15;
            const float bv = bias[col];
#pragma unroll
            for (int r = 0; r < 4; ++r)
                store_out(&Cmat[(size_t)(row + r) * N + col], acc[i][j][r] + bv);
        }
    }
}

// ---------------------------------------------------------------------------
// Flash attention: one block per (q-tile of 128, head, batch).
// qkv layout: [B*N, 3*C] row-major bf16. Q cols [0,768), K [768,1536),
// V [1536,2304); head h at col offset h*64. Each wave owns 32 complete query
// rows -> softmax reductions are quad-local shfl_xor. P round-trips through
// LDS to re-enter PV in A-layout; V transposed in LDS for B-frags.
// ---------------------------------------------------------------------------
#define NTOK 1024
#define CCH  768
#define HD   64

__global__ __launch_bounds__(256, 2)
void attn_fused(const unsigned short* __restrict__ qkv,
                unsigned short* __restrict__ aout)
{
    // Ps[128][136] aliases Ks[128][72] (Ks dead after QK^T). Vt separate.
    __shared__ __align__(16) unsigned short smem[17408 + 8704];  // 52224 B
    unsigned short (*Ks)[72]  = (unsigned short (*)[72])  smem;
    unsigned short (*Ps)[136] = (unsigned short (*)[136]) smem;
    unsigned short (*Vt)[136] = (unsigned short (*)[136])(smem + 17408);

    const int tid  = threadIdx.x;
    const int wave = tid >> 6;
    const int lane = tid & 63;
    const int quad = lane >> 4;
    const int l15  = lane & 15;

    const int qt = blockIdx.x;   // 0..7
    const int h  = blockIdx.y;   // 0..11
    const int b  = blockIdx.z;   // 0..7

    const size_t rs = 3 * CCH;   // 2304
    const unsigned short* Qg = qkv + (size_t)b * NTOK * rs + (size_t)h * HD;
    const unsigned short* Kg = Qg + CCH;
    const unsigned short* Vg = Qg + 2 * CCH;

    const int q0 = qt * 128;

    // Q fragments in registers (A-layout: m=l15, k=quad*8+j), d=64 -> 2 ksteps
    bf16x8 qf[2][2];
#pragma unroll
    for (int i = 0; i < 2; ++i)
#pragma unroll
        for (int ks = 0; ks < 2; ++ks)
            qf[i][ks] = *(const bf16x8*)(Qg + (size_t)(q0 + wave * 32 + i * 16 + l15) * rs
                                             + ks * 32 + quad * 8);

    f32x4 oacc[2][4];
#pragma unroll
    for (int i = 0; i < 2; ++i)
#pragma unroll
        for (int n = 0; n < 4; ++n) oacc[i][n] = (f32x4){0.f, 0.f, 0.f, 0.f};

    float mrow[2][4], lrow[2][4];
#pragma unroll
    for (int i = 0; i < 2; ++i)
#pragma unroll
        for (int r = 0; r < 4; ++r) { mrow[i][r] = -INFINITY; lrow[i][r] = 0.f; }

    const int ldr = tid >> 1;        // 0..127
    const int ldc = (tid & 1) * 32;  // 0 or 32

    for (int t = 0; t < 8; ++t) {
        __syncthreads();  // prev iter's Ps/Vt reads done before overwrite

        {   // K tile: 128 keys x 64 dims, row-major, d contiguous
            const unsigned short* src = Kg + (size_t)(t * 128 + ldr) * rs + ldc;
            bf16x8 a0 = *(const bf16x8*)(src);
            bf16x8 a1 = *(const bf16x8*)(src + 8);
            bf16x8 a2 = *(const bf16x8*)(src + 16);
            bf16x8 a3 = *(const bf16x8*)(src + 24);
            *(bf16x8*)&Ks[ldr][ldc]      = a0;
            *(bf16x8*)&Ks[ldr][ldc + 8]  = a1;
            *(bf16x8*)&Ks[ldr][ldc + 16] = a2;
            *(bf16x8*)&Ks[ldr][ldc + 24] = a3;
        }
        {   // V tile transposed: Vt[d][kc]
            const unsigned short* src = Vg + (size_t)(t * 128 + ldr) * rs + ldc;
            bf16x8 v0 = *(const bf16x8*)(src);
            bf16x8 v1 = *(const bf16x8*)(src + 8);
            bf16x8 v2 = *(const bf16x8*)(src + 16);
            bf16x8 v3 = *(const bf16x8*)(src + 24);
#pragma unroll
            for (int j = 0; j < 8; ++j) {
                Vt[ldc + j][ldr]      = (unsigned short)v0[j];
                Vt[ldc + 8 + j][ldr]  = (unsigned short)v1[j];
                Vt[ldc + 16 + j][ldr] = (unsigned short)v2[j];
                Vt[ldc + 24 + j][ldr] = (unsigned short)v3[j];
            }
        }
        __syncthreads();

        // S = Q K^T (raw; scale folded into softmax)
        f32x4 sacc[2][8];
#pragma unroll
        for (int i = 0; i < 2; ++i)
#pragma unroll
            for (int j = 0; j < 8; ++j) sacc[i][j] = (f32x4){0.f, 0.f, 0.f, 0.f};

#pragma unroll
        for (int ks = 0; ks < 2; ++ks) {
            bf16x8 kf[8];
#pragma unroll
            for (int j = 0; j < 8; ++j)
                kf[j] = *(const bf16x8*)&Ks[j * 16 + l15][ks * 32 + quad * 8];
#pragma unroll
            for (int i = 0; i < 2; ++i)
#pragma unroll
                for (int j = 0; j < 8; ++j)
                    sacc[i][j] = __builtin_amdgcn_mfma_f32_16x16x32_bf16(qf[i][ks], kf[j], sacc[i][j], 0, 0, 0);
        }

        __syncthreads();  // all waves done reading Ks before Ps (alias) writes

        // online softmax, scale = 0.125
#pragma unroll
        for (int i = 0; i < 2; ++i) {
#pragma unroll
            for (int r = 0; r < 4; ++r) {
                float mt = sacc[i][0][r];
#pragma unroll
                for (int j = 1; j < 8; ++j) mt = fmaxf(mt, sacc[i][j][r]);
                mt = fmaxf(mt, __shfl_xor(mt, 1));
                mt = fmaxf(mt, __shfl_xor(mt, 2));
                mt = fmaxf(mt, __shfl_xor(mt, 4));
                mt = fmaxf(mt, __shfl_xor(mt, 8));
                mt *= 0.125f;
                const float mnew  = fmaxf(mrow[i][r], mt);
                const float alpha = __expf(mrow[i][r] - mnew);  // 0 on first tile
                mrow[i][r] = mnew;
                float rsum = 0.f;
#pragma unroll
                for (int j = 0; j < 8; ++j) {
                    const float p = __expf(fmaf(sacc[i][j][r], 0.125f, -mnew));
                    sacc[i][j][r] = p;
                    rsum += p;
                }
                rsum += __shfl_xor(rsum, 1);
                rsum += __shfl_xor(rsum, 2);
                rsum += __shfl_xor(rsum, 4);
                rsum += __shfl_xor(rsum, 8);
                lrow[i][r] = lrow[i][r] * alpha + rsum;
#pragma unroll
                for (int n = 0; n < 4; ++n) oacc[i][n][r] *= alpha;
            }
        }

        // P -> LDS (bf16), C-layout rows
#pragma unroll
        for (int i = 0; i < 2; ++i)
#pragma unroll
            for (int j = 0; j < 8; ++j)
#pragma unroll
                for (int r = 0; r < 4; ++r)
                    Ps[wave * 32 + i * 16 + quad * 4 + r][j * 16 + l15] = f2bf(sacc[i][j][r]);

        __syncthreads();

        // O += P V   (K=128 over key cols, N=64 over dims)
#pragma unroll
        for (int ks = 0; ks < 4; ++ks) {
            bf16x8 pf[2], vf[4];
#pragma unroll
            for (int i = 0; i < 2; ++i)
                pf[i] = *(const bf16x8*)&Ps[wave * 32 + i * 16 + l15][ks * 32 + quad * 8];
#pragma unroll
            for (int n = 0; n < 4; ++n)
                vf[n] = *(const bf16x8*)&Vt[n * 16 + l15][ks * 32 + quad * 8];
#pragma unroll
            for (int i = 0; i < 2; ++i)
#pragma unroll
                for (int n = 0; n < 4; ++n)
                    oacc[i][n] = __builtin_amdgcn_mfma_f32_16x16x32_bf16(pf[i], vf[n], oacc[i][n], 0, 0, 0);
        }
    }

    // epilogue: normalize, write attn_out[b*N+q][h*64+d] (bf16)
#pragma unroll
    for (int i = 0; i < 2; ++i) {
#pragma unroll
        for (int r = 0; r < 4; ++r) {
            const int qrow  = q0 + wave * 32 + i * 16 + quad * 4 + r;
            const float inv = 1.f / lrow[i][r];
#pragma unroll
            for (int n = 0; n < 4; ++n) {
                const int dcol = n * 16 + l15;
                aout[(size_t)(b * NTOK + qrow) * CCH + h * HD + dcol] = f2bf(oacc[i][n][r] * inv);
            }
        }
    }
}

// ---------------------------------------------------------------------------
extern "C" void kernel_launch(void* const* d_in, const int* in_sizes, int n_in,
                              void* d_out, int out_size, void* d_ws, size_t ws_size,
                              hipStream_t stream)
{
    // inputs are fp32 per the reference
    const float* x      = (const float*)d_in[0];  // [8192,768]
    const float* qkv_w  = (const float*)d_in[1];  // [2304,768]
    const float* qkv_b  = (const float*)d_in[2];  // [2304]
    const float* proj_w = (const float*)d_in[3];  // [768,768]
    const float* proj_b = (const float*)d_in[4];  // [768]
    float* out = (float*)d_out;                   // [8192,768] fp32

    // workspace layout (all bf16 = unsigned short)
    unsigned short* qkv = (unsigned short*)d_ws;             // [8192,2304]
    unsigned short* att = qkv + (size_t)8192 * 2304;         // [8192,768]
    unsigned short* xb  = att + (size_t)8192 * 768;          // [8192,768]
    unsigned short* wqb = xb  + (size_t)8192 * 768;          // [2304,768]
    unsigned short* wpb = wqb + (size_t)2304 * 768;          // [768,768]

    dim3 blk(256);
    // fp32 -> bf16 conversions
    f32_to_bf16<<<dim3((8192 * 768 / 4 + 255) / 256), blk, 0, stream>>>(x, xb, 8192 * 768 / 4);
    f32_to_bf16<<<dim3((2304 * 768 / 4 + 255) / 256), blk, 0, stream>>>(qkv_w, wqb, 2304 * 768 / 4);
    f32_to_bf16<<<dim3((768 * 768 / 4 + 255) / 256), blk, 0, stream>>>(proj_w, wpb, 768 * 768 / 4);

    // QKV projection: M=8192, N=2304, K=768 -> bf16 intermediate
    gemm_bt_128<unsigned short><<<dim3(64, 18), blk, 0, stream>>>(xb, wqb, qkv_b, qkv, 8192, 2304, 768);
    // fused attention per (qtile, head, batch) -> bf16 intermediate
    attn_fused<<<dim3(8, 12, 8), blk, 0, stream>>>(qkv, att);
    // output projection: M=8192, N=768, K=768 -> fp32 output
    gemm_bt_128<float><<<dim3(64, 6), blk, 0, stream>>>(att, wpb, proj_b, out, 8192, 768, 768);
}